// Round 1
// baseline (301.890 us; speedup 1.0000x reference)
//
#include <hip/hip_runtime.h>
#include <math.h>

#define PATCH 96
#define STRIDE 48
#define NH 21
#define NW 21
#define NP (NH * NW)              // 441 patches per (b,c)
#define BATCH 8
#define CHAN 4
#define NBC (BATCH * CHAN)        // 32
#define IMG_H 1056
#define IMG_W 1056
#define NHB 44                    // 24-row half-bands
#define NCHUNK 22                 // 48-col chunks
#define NSTAT 6                   // s1, s2, gxi, gxb, gyi, gyb
#define NPIX 9216.0f
#define NGRAD 9120.0f
#define SLAB (NHB * NCHUNK * NSTAT)   // 5808 floats per bc

// ---------------------------------------------------------------------------
// Single fused kernel. Grid = 1408 blocks (bc x half-band), 320 threads.
//
// Stage A (all blocks): band stats exactly as the previous band_stats_kernel.
//   264 active threads own 4 contiguous cols across 24 rows (+1 boundary row
//   for gy). Per-chunk partials merged via LDS atomics; 132 floats -> pf.
// Stage B (last-arriving block per bc, via device-scope ticket): stage the
//   bc's 44x22x6 slab in LDS, compute 441 patch features, reduce to per-bc
//   means -> featsG. Reads use agent-scope atomic loads (per-XCD L2s are not
//   coherent and the harness poison fill may have planted stale lines).
// Stage C (last of the 32 stage-B blocks, via a second ticket): register-
//   resident Gauss-Jordan on the 12x24 augmented system in wave 0, then
//   Mahalanobis per batch + mean -> out.
//
// Coherence discipline (Guideline 16): writers fence (__threadfence, agent
// scope -> L2 writeback) BEFORE the device-scope atomicAdd ticket; readers
// fence after winning the ticket and load with AGENT-scope atomic loads.
// ---------------------------------------------------------------------------
__global__ __launch_bounds__(320, 5) void fused_kernel(
    const float* __restrict__ x, float* __restrict__ pf,
    float* __restrict__ featsG, int* __restrict__ cnt,
    const float* __restrict__ mu0_full, const float* __restrict__ cov_full,
    float* __restrict__ out) {
  __shared__ float S[SLAB];              // 23.2 KB; stage A uses first 132
  __shared__ float wsum[5][3];
  __shared__ double inv_s[12][12];
  __shared__ float fin_s[96 + BATCH];
  __shared__ int ticket_s;

  const int t = threadIdx.x;             // 0..319
  const int bc = blockIdx.x / NHB;
  const int hb = blockIdx.x - bc * NHB;

  // ---------------- Stage A: band stats (identical math to prior kernel) ---
  const bool active = t < 264;
  const int tc = active ? t : 263;       // clamp idle lanes to a safe column
  // right-neighbor offset: +4 except at image edge (clamped -> d4==0, lands
  // in the never-read gxb of chunk 21)
  const int noff = (tc == 263) ? 3 : 4;

  const float* rowbase = x + (size_t)bc * (IMG_H * IMG_W)
                           + (size_t)(hb * 24) * IMG_W
                           + (size_t)(4 * tc);

  float s1 = 0.f, s2 = 0.f, gxi = 0.f, gxb = 0.f, gyi = 0.f, gyb = 0.f;
  const bool bnd_is_gxb = ((tc % 12) == 11);   // last quad of its chunk

#define SUMS_GX(A, nxt)                                                  \
  do {                                                                   \
    s1 += (A).x + (A).y + (A).z + (A).w;                                 \
    s2 += (A).x * (A).x + (A).y * (A).y + (A).z * (A).z + (A).w * (A).w; \
    float d1 = (A).y - (A).x, d2 = (A).z - (A).y, d3 = (A).w - (A).z;    \
    float d4 = (nxt) - (A).w;                                            \
    gxi += d1 * d1 + d2 * d2 + d3 * d3;                                  \
    float bd = d4 * d4;                                                  \
    if (bnd_is_gxb) gxb += bd; else gxi += bd;                           \
  } while (0)

  float4 prev;
  {  // row 0 (no gy)
    const float4 A = *(const float4*)rowbase;
    const float nxt = rowbase[noff];
    SUMS_GX(A, nxt);
    prev = A;
  }
#pragma unroll 4
  for (int r = 1; r < 24; ++r) {
    const float4 A = *(const float4*)(rowbase + (size_t)r * IMG_W);
    const float nxt = rowbase[(size_t)r * IMG_W + noff];
    SUMS_GX(A, nxt);
    const float e0 = A.x - prev.x, e1 = A.y - prev.y,
                e2 = A.z - prev.z, e3 = A.w - prev.w;
    gyi += e0 * e0 + e1 * e1 + e2 * e2 + e3 * e3;
    prev = A;
  }
  if (hb != NHB - 1) {   // boundary gy pair (row 23 <-> next hb's row 0)
    const float4 A = *(const float4*)(rowbase + (size_t)24 * IMG_W);
    const float e0 = A.x - prev.x, e1 = A.y - prev.y,
                e2 = A.z - prev.z, e3 = A.w - prev.w;
    gyb = e0 * e0 + e1 * e1 + e2 * e2 + e3 * e3;
  }
#undef SUMS_GX

  for (int i = t; i < NCHUNK * NSTAT; i += 320) S[i] = 0.f;
  __syncthreads();
  if (active) {
    const int chunk = tc / 12;
    atomicAdd(&S[chunk * NSTAT + 0], s1);
    atomicAdd(&S[chunk * NSTAT + 1], s2);
    atomicAdd(&S[chunk * NSTAT + 2], gxi);
    atomicAdd(&S[chunk * NSTAT + 3], gxb);
    atomicAdd(&S[chunk * NSTAT + 4], gyi);
    atomicAdd(&S[chunk * NSTAT + 5], gyb);
  }
  __syncthreads();

  // publish partials (wave 0 only -> only one wbl2 fence per block)
  if (t < 64) {
    float* dst = pf + (size_t)(bc * NHB + hb) * (NCHUNK * NSTAT);
    for (int i = t; i < NCHUNK * NSTAT; i += 64) dst[i] = S[i];
    __threadfence();                      // release: drain + L2 writeback
  }
  __syncthreads();
  if (t == 0) ticket_s = atomicAdd(&cnt[bc], 1);   // device-scope
  __syncthreads();
  if (ticket_s != NHB - 1) return;

  // ---------------- Stage B: last block for this bc -> patch features ------
  __threadfence();                        // acquire: invalidate stale lines
  {
    const float* src = pf + (size_t)bc * SLAB;
    for (int i = t; i < SLAB; i += 320)
      S[i] = __hip_atomic_load(&src[i], __ATOMIC_RELAXED,
                               __HIP_MEMORY_SCOPE_AGENT);
  }
  __syncthreads();

  float am = 0.f, av = 0.f, ag = 0.f;
#define AT(h, c, s) S[((h) * NCHUNK + (c)) * NSTAT + (s)]
  for (int p = t; p < NP; p += 320) {     // t<121 handles 2 patches
    const int ph = p / NW, pw = p - ph * NW;
    const int h0 = 2 * ph;
    float S1 = 0.f, S2 = 0.f, Gx = 0.f, Gy = 0.f;
#pragma unroll
    for (int hh = 0; hh < 4; ++hh) {
      const int h = h0 + hh;
      S1 += AT(h, pw, 0) + AT(h, pw + 1, 0);
      S2 += AT(h, pw, 1) + AT(h, pw + 1, 1);
      Gx += AT(h, pw, 2) + AT(h, pw, 3) + AT(h, pw + 1, 2);
      Gy += AT(h, pw, 4) + AT(h, pw + 1, 4);
    }
#pragma unroll
    for (int hh = 0; hh < 3; ++hh) {
      const int h = h0 + hh;
      Gy += AT(h, pw, 5) + AT(h, pw + 1, 5);
    }
    am += S1 / NPIX;
    av += (S2 - S1 * S1 / NPIX) / (NPIX - 1.f);
    ag += sqrtf((Gx + Gy) / NGRAD);
  }
#undef AT
#pragma unroll
  for (int off = 32; off > 0; off >>= 1) {
    am += __shfl_xor(am, off);
    av += __shfl_xor(av, off);
    ag += __shfl_xor(ag, off);
  }
  const int wave = t >> 6;
  if ((t & 63) == 0) { wsum[wave][0] = am; wsum[wave][1] = av; wsum[wave][2] = ag; }
  __syncthreads();
  if (t == 0) {
    float m = 0.f, v = 0.f, g = 0.f;
#pragma unroll
    for (int w = 0; w < 5; ++w) { m += wsum[w][0]; v += wsum[w][1]; g += wsum[w][2]; }
    const int b = bc / CHAN, c = bc - b * CHAN;
    featsG[b * 12 + 0 + c] = m / (float)NP;
    featsG[b * 12 + 4 + c] = v / (float)NP;
    featsG[b * 12 + 8 + c] = g / (float)NP;
    __threadfence();                      // release featsG
    ticket_s = atomicAdd(&cnt[NBC], 1);   // global ticket
  }
  __syncthreads();
  if (ticket_s != NBC - 1) return;

  // ---------------- Stage C: global last block -> finalize -----------------
  __threadfence();                        // acquire
  if (t < 96)
    fin_s[t] = __hip_atomic_load(&featsG[t], __ATOMIC_RELAXED,
                                 __HIP_MEMORY_SCOPE_AGENT);
  __syncthreads();

  if (t < 64) {   // wave 0: register-resident Gauss-Jordan, lane c owns col c
    double M[12];
#pragma unroll
    for (int r = 0; r < 12; ++r) {
      double v = 0.0;
      if (t < 12) v = (double)cov_full[r * 36 + t];
      else if (t < 24) v = (t - 12 == r) ? 1.0 : 0.0;
      M[r] = v;
    }
#pragma unroll
    for (int k = 0; k < 12; ++k) {
      const double piv = __shfl(M[k], k);
      const double ip = 1.0 / piv;
      M[k] *= ip;
#pragma unroll
      for (int r = 0; r < 12; ++r) {
        if (r == k) continue;
        const double f = __shfl(M[r], k);   // old M[r][k], read before update
        M[r] -= f * M[k];
      }
    }
    if (t >= 12 && t < 24) {
      const int j = t - 12;
#pragma unroll
      for (int r = 0; r < 12; ++r) inv_s[r][j] = M[r];
    }
  }
  __syncthreads();

  if (t < BATCH) {
    double acc = 0.0;
    double d[12];
#pragma unroll
    for (int i = 0; i < 12; ++i)
      d[i] = (double)fin_s[t * 12 + i] - (double)mu0_full[i];
#pragma unroll
    for (int i = 0; i < 12; ++i) {
      double row = 0.0;
#pragma unroll
      for (int j = 0; j < 12; ++j) row += inv_s[i][j] * d[j];
      acc += d[i] * row;
    }
    fin_s[96 + t] = (float)sqrt(acc);
  }
  __syncthreads();
  if (t == 0) {
    float m = 0.f;
#pragma unroll
    for (int b = 0; b < BATCH; ++b) m += fin_s[96 + b];
    out[0] = m / (float)BATCH;
  }
}

extern "C" void kernel_launch(void* const* d_in, const int* in_sizes, int n_in,
                              void* d_out, int out_size, void* d_ws, size_t ws_size,
                              hipStream_t stream) {
  const float* x   = (const float*)d_in[0];
  const float* mu0 = (const float*)d_in[1];
  const float* cov = (const float*)d_in[2];
  float* out = (float*)d_out;
  float* pf     = (float*)d_ws;                         // 32*5808 floats = 743 KB
  float* featsG = pf + (size_t)NBC * SLAB;              // 96 floats
  int* cnt      = (int*)(featsG + 96);                  // 32 per-bc + 1 global

  // counters live in poisoned workspace -> must zero every iteration
  hipMemsetAsync(cnt, 0, (NBC + 1) * sizeof(int), stream);
  fused_kernel<<<NBC * NHB, 320, 0, stream>>>(x, pf, featsG, cnt, mu0, cov, out);
}

// Round 2
// 286.839 us; speedup vs baseline: 1.0525x; 1.0525x over previous
//
#include <hip/hip_runtime.h>
#include <math.h>

#define PATCH 96
#define STRIDE 48
#define NH 21
#define NW 21
#define NP (NH * NW)              // 441 patches per (b,c)
#define BATCH 8
#define CHAN 4
#define NBC (BATCH * CHAN)        // 32
#define IMG_H 1056
#define IMG_W 1056
#define NHB 44                    // 24-row half-bands
#define NCHUNK 22                 // 48-col chunks
#define NSTAT 6                   // s1, s2, gxi, gxb, gyi, gyb
#define NPIX 9216.0f
#define NGRAD 9120.0f
#define SLAB (NHB * NCHUNK * NSTAT)   // 5808 floats per bc

// ---------------------------------------------------------------------------
// Phase 1: one block per (bc, half-band). 264 active threads (of 320) own 4
// contiguous cols across 24 rows (+1 boundary row for gy). Plain float4 load;
// the right gx neighbor is the NEXT LANE's A.x -> __shfl_down(A.x,1), with a
// scalar load only for the 5 wave-boundary lanes (t&63==63). This halves the
// VMEM instruction count vs the load-per-row variant. Per-chunk partials
// merged via LDS atomics; 132 floats per block.
// NOTE: no min-waves launch_bounds — round 1 showed (320,5) forces VGPR=32,
// serializing the load pipeline (5% BW). Let the allocator breathe.
// ---------------------------------------------------------------------------
__global__ __launch_bounds__(320) void band_stats_kernel(
    const float* __restrict__ x, float* __restrict__ pf, int* __restrict__ cnt) {
  __shared__ float acc[NCHUNK * NSTAT];   // 528 B

  const int t = threadIdx.x;              // 0..319
  const int bc = blockIdx.x / NHB;
  const int hb = blockIdx.x - bc * NHB;
  // zero the phase-2 ticket counter (poisoned workspace); visible to the next
  // kernel via the dispatch boundary
  if (blockIdx.x == 0 && t == 0) cnt[0] = 0;

  const bool active = t < 264;
  const int tc = active ? t : 263;        // clamp idle lanes to a safe column
  const bool edge = ((t & 63) == 63);     // last lane of wave: no shfl source
  // edge-lane scalar offset: +4 except at image edge (clamped -> stays in
  // bounds; lands in the never-read gxb of chunk 21)
  const int noff = (tc == 263) ? 3 : 4;

  const float* rowbase = x + (size_t)bc * (IMG_H * IMG_W)
                           + (size_t)(hb * 24) * IMG_W
                           + (size_t)(4 * tc);

  float s1 = 0.f, s2 = 0.f, gxi = 0.f, gxb = 0.f, gyi = 0.f, gyb = 0.f;
  const bool bnd_is_gxb = ((tc % 12) == 11);   // last quad of its chunk

#define SUMS_GX(A, nxt)                                                  \
  do {                                                                   \
    s1 += (A).x + (A).y + (A).z + (A).w;                                 \
    s2 += (A).x * (A).x + (A).y * (A).y + (A).z * (A).z + (A).w * (A).w; \
    float d1 = (A).y - (A).x, d2 = (A).z - (A).y, d3 = (A).w - (A).z;    \
    float d4 = (nxt) - (A).w;                                            \
    gxi += d1 * d1 + d2 * d2 + d3 * d3;                                  \
    float bd = d4 * d4;                                                  \
    if (bnd_is_gxb) gxb += bd; else gxi += bd;                           \
  } while (0)

  float4 prev;
  {  // row 0 (no gy)
    const float4 A = *(const float4*)rowbase;
    float nxt = __shfl_down(A.x, 1);
    if (edge) nxt = rowbase[noff];
    SUMS_GX(A, nxt);
    prev = A;
  }
#pragma unroll 4
  for (int r = 1; r < 24; ++r) {
    const float4 A = *(const float4*)(rowbase + (size_t)r * IMG_W);
    float nxt = __shfl_down(A.x, 1);
    if (edge) nxt = rowbase[(size_t)r * IMG_W + noff];
    SUMS_GX(A, nxt);
    const float e0 = A.x - prev.x, e1 = A.y - prev.y,
                e2 = A.z - prev.z, e3 = A.w - prev.w;
    gyi += e0 * e0 + e1 * e1 + e2 * e2 + e3 * e3;
    prev = A;
  }
  if (hb != NHB - 1) {   // boundary gy pair (row 23 <-> row 24 == next hb's row 0)
    const float4 A = *(const float4*)(rowbase + (size_t)24 * IMG_W);
    const float e0 = A.x - prev.x, e1 = A.y - prev.y,
                e2 = A.z - prev.z, e3 = A.w - prev.w;
    gyb = e0 * e0 + e1 * e1 + e2 * e2 + e3 * e3;
  }
#undef SUMS_GX

  for (int i = t; i < NCHUNK * NSTAT; i += 320) acc[i] = 0.f;
  __syncthreads();
  if (active) {
    const int chunk = tc / 12;
    atomicAdd(&acc[chunk * NSTAT + 0], s1);
    atomicAdd(&acc[chunk * NSTAT + 1], s2);
    atomicAdd(&acc[chunk * NSTAT + 2], gxi);
    atomicAdd(&acc[chunk * NSTAT + 3], gxb);
    atomicAdd(&acc[chunk * NSTAT + 4], gyi);
    atomicAdd(&acc[chunk * NSTAT + 5], gyb);
  }
  __syncthreads();
  float* dst = pf + (size_t)(bc * NHB + hb) * (NCHUNK * NSTAT);
  for (int i = t; i < NCHUNK * NSTAT; i += 320) dst[i] = acc[i];
}

// ---------------------------------------------------------------------------
// Phase 2+3 merged: one block per bc (32 blocks). Stage the bc's 44x22x6 slab
// in LDS; thread p<441 combines its 4 half-bands x 2 chunks into
// (mu, var, gmag); block-reduce to per-bc means -> featsG. The last-arriving
// block (device-scope ticket; only 32 fences, cheap) then runs the
// register-resident Gauss-Jordan + Mahalanobis finalize.
// ---------------------------------------------------------------------------
__global__ __launch_bounds__(512) void patch_finalize_kernel(
    const float* __restrict__ pf, float* __restrict__ featsG,
    int* __restrict__ cnt, const float* __restrict__ mu0_full,
    const float* __restrict__ cov_full, float* __restrict__ out) {
  __shared__ float S[SLAB];                   // 23.2 KB
  __shared__ float wsum[8][3];
  __shared__ double inv_s[12][12];
  __shared__ float fin_s[96 + BATCH];
  __shared__ int ticket_s;

  const int bc = blockIdx.x;
  const int t = threadIdx.x;
  const float* src = pf + (size_t)bc * SLAB;
  for (int i = t; i < SLAB; i += 512) S[i] = src[i];
  __syncthreads();

  float fmu = 0.f, fvar = 0.f, fg = 0.f;
  if (t < NP) {
    const int ph = t / NW, pw = t - ph * NW;
    const int h0 = 2 * ph;
#define AT(h, c, s) S[((h) * NCHUNK + (c)) * NSTAT + (s)]
    float S1 = 0.f, S2 = 0.f, Gx = 0.f, Gy = 0.f;
#pragma unroll
    for (int hh = 0; hh < 4; ++hh) {
      const int h = h0 + hh;
      S1 += AT(h, pw, 0) + AT(h, pw + 1, 0);
      S2 += AT(h, pw, 1) + AT(h, pw + 1, 1);
      Gx += AT(h, pw, 2) + AT(h, pw, 3) + AT(h, pw + 1, 2);
      Gy += AT(h, pw, 4) + AT(h, pw + 1, 4);
    }
#pragma unroll
    for (int hh = 0; hh < 3; ++hh) {
      const int h = h0 + hh;
      Gy += AT(h, pw, 5) + AT(h, pw + 1, 5);
    }
#undef AT
    fmu = S1 / NPIX;
    fvar = (S2 - S1 * S1 / NPIX) / (NPIX - 1.f);
    fg = sqrtf((Gx + Gy) / NGRAD);
  }
#pragma unroll
  for (int off = 32; off > 0; off >>= 1) {
    fmu += __shfl_xor(fmu, off);
    fvar += __shfl_xor(fvar, off);
    fg += __shfl_xor(fg, off);
  }
  const int wave = t >> 6;
  if ((t & 63) == 0) { wsum[wave][0] = fmu; wsum[wave][1] = fvar; wsum[wave][2] = fg; }
  __syncthreads();
  if (t == 0) {
    float m = 0.f, v = 0.f, g = 0.f;
#pragma unroll
    for (int w = 0; w < 8; ++w) { m += wsum[w][0]; v += wsum[w][1]; g += wsum[w][2]; }
    const int b = bc / CHAN, c = bc - b * CHAN;
    featsG[b * 12 + 0 + c] = m / (float)NP;
    featsG[b * 12 + 4 + c] = v / (float)NP;
    featsG[b * 12 + 8 + c] = g / (float)NP;
    __threadfence();                      // release featsG (L2 writeback)
    ticket_s = atomicAdd(cnt, 1);         // device-scope ticket
  }
  __syncthreads();
  if (ticket_s != NBC - 1) return;

  // ---- last block: finalize ----
  __threadfence();                        // acquire: invalidate stale lines
  if (t < 96)
    fin_s[t] = __hip_atomic_load(&featsG[t], __ATOMIC_RELAXED,
                                 __HIP_MEMORY_SCOPE_AGENT);
  __syncthreads();

  if (t < 64) {   // wave 0: register-resident Gauss-Jordan, lane c owns col c
    double M[12];
#pragma unroll
    for (int r = 0; r < 12; ++r) {
      double v = 0.0;
      if (t < 12) v = (double)cov_full[r * 36 + t];
      else if (t < 24) v = (t - 12 == r) ? 1.0 : 0.0;
      M[r] = v;
    }
#pragma unroll
    for (int k = 0; k < 12; ++k) {
      const double piv = __shfl(M[k], k);
      const double ip = 1.0 / piv;
      M[k] *= ip;
#pragma unroll
      for (int r = 0; r < 12; ++r) {
        if (r == k) continue;
        const double f = __shfl(M[r], k);   // old M[r][k], read before update
        M[r] -= f * M[k];
      }
    }
    if (t >= 12 && t < 24) {
      const int j = t - 12;
#pragma unroll
      for (int r = 0; r < 12; ++r) inv_s[r][j] = M[r];
    }
  }
  __syncthreads();

  if (t < BATCH) {
    double acc = 0.0;
    double d[12];
#pragma unroll
    for (int i = 0; i < 12; ++i)
      d[i] = (double)fin_s[t * 12 + i] - (double)mu0_full[i];
#pragma unroll
    for (int i = 0; i < 12; ++i) {
      double row = 0.0;
#pragma unroll
      for (int j = 0; j < 12; ++j) row += inv_s[i][j] * d[j];
      acc += d[i] * row;
    }
    fin_s[96 + t] = (float)sqrt(acc);
  }
  __syncthreads();
  if (t == 0) {
    float m = 0.f;
#pragma unroll
    for (int b = 0; b < BATCH; ++b) m += fin_s[96 + b];
    out[0] = m / (float)BATCH;
  }
}

extern "C" void kernel_launch(void* const* d_in, const int* in_sizes, int n_in,
                              void* d_out, int out_size, void* d_ws, size_t ws_size,
                              hipStream_t stream) {
  const float* x   = (const float*)d_in[0];
  const float* mu0 = (const float*)d_in[1];
  const float* cov = (const float*)d_in[2];
  float* out = (float*)d_out;
  float* pf     = (float*)d_ws;                         // 32*5808 floats = 743 KB
  float* featsG = pf + (size_t)NBC * SLAB;              // 96 floats
  int* cnt      = (int*)(featsG + 96);                  // 1 ticket counter

  band_stats_kernel<<<NBC * NHB, 320, 0, stream>>>(x, pf, cnt);
  patch_finalize_kernel<<<NBC, 512, 0, stream>>>(pf, featsG, cnt, mu0, cov, out);
}

// Round 3
// 228.036 us; speedup vs baseline: 1.3239x; 1.2579x over previous
//
#include <hip/hip_runtime.h>
#include <math.h>

#define PATCH 96
#define STRIDE 48
#define NH 21
#define NW 21
#define NP (NH * NW)              // 441 patches per (b,c)
#define BATCH 8
#define CHAN 4
#define NBC (BATCH * CHAN)        // 32
#define IMG_H 1056
#define IMG_W 1056
#define NHB 44                    // 24-row half-bands
#define NCHUNK 22                 // 48-col chunks
#define NSTAT 6                   // s1, s2, gxi, gxb, gyi, gyb
#define NPIX 9216.0f
#define NGRAD 9120.0f
#define SLAB (NHB * NCHUNK * NSTAT)   // 5808 floats per bc

// ---------------------------------------------------------------------------
// Phase 1: one block per (bc, half-band). 264 active threads (of 320) own 4
// contiguous cols across 24 rows (+1 boundary row for gy). Plain float4 load
// + one overlapping scalar load for the right gx neighbor (L1 hit).
// ROUND-0 EXACT FORM — rounds 1/2 proved:
//   * min-waves launch_bounds (,5) forces VGPR=32 and serializes loads (5% BW)
//   * replacing the scalar neighbor load with __shfl_down creates a per-row
//     vmcnt(0) dependency chain -> 3x slower. The redundant scalar loads are
//     independent L1 hits; ILP is what this kernel lives on. Do not "fix".
// Per-chunk partials merged via LDS atomics; 132 floats per block.
// ---------------------------------------------------------------------------
__global__ __launch_bounds__(320) void band_stats_kernel(
    const float* __restrict__ x, float* __restrict__ pf, int* __restrict__ cnt) {
  __shared__ float acc[NCHUNK * NSTAT];   // 528 B

  const int t = threadIdx.x;              // 0..319
  const int bc = blockIdx.x / NHB;
  const int hb = blockIdx.x - bc * NHB;
  // zero the phase-2 ticket counter (poisoned workspace); visible to the next
  // kernel via the dispatch boundary
  if (blockIdx.x == 0 && t == 0) cnt[0] = 0;

  const bool active = t < 264;
  const int tc = active ? t : 263;        // clamp idle lanes to a safe column
  // right-neighbor offset: +4 except at image edge (clamped -> d4==0, lands
  // in the never-read gxb of chunk 21)
  const int noff = (tc == 263) ? 3 : 4;

  const float* rowbase = x + (size_t)bc * (IMG_H * IMG_W)
                           + (size_t)(hb * 24) * IMG_W
                           + (size_t)(4 * tc);

  float s1 = 0.f, s2 = 0.f, gxi = 0.f, gxb = 0.f, gyi = 0.f, gyb = 0.f;
  const bool bnd_is_gxb = ((tc % 12) == 11);   // last quad of its chunk

#define SUMS_GX(A, nxt)                                                  \
  do {                                                                   \
    s1 += (A).x + (A).y + (A).z + (A).w;                                 \
    s2 += (A).x * (A).x + (A).y * (A).y + (A).z * (A).z + (A).w * (A).w; \
    float d1 = (A).y - (A).x, d2 = (A).z - (A).y, d3 = (A).w - (A).z;    \
    float d4 = (nxt) - (A).w;                                            \
    gxi += d1 * d1 + d2 * d2 + d3 * d3;                                  \
    float bd = d4 * d4;                                                  \
    if (bnd_is_gxb) gxb += bd; else gxi += bd;                           \
  } while (0)

  float4 prev;
  {  // row 0 (no gy)
    const float4 A = *(const float4*)rowbase;
    const float nxt = rowbase[noff];
    SUMS_GX(A, nxt);
    prev = A;
  }
#pragma unroll 4
  for (int r = 1; r < 24; ++r) {
    const float4 A = *(const float4*)(rowbase + (size_t)r * IMG_W);
    const float nxt = rowbase[(size_t)r * IMG_W + noff];
    SUMS_GX(A, nxt);
    const float e0 = A.x - prev.x, e1 = A.y - prev.y,
                e2 = A.z - prev.z, e3 = A.w - prev.w;
    gyi += e0 * e0 + e1 * e1 + e2 * e2 + e3 * e3;
    prev = A;
  }
  if (hb != NHB - 1) {   // boundary gy pair (row 23 <-> row 24 == next hb's row 0)
    const float4 A = *(const float4*)(rowbase + (size_t)24 * IMG_W);
    const float e0 = A.x - prev.x, e1 = A.y - prev.y,
                e2 = A.z - prev.z, e3 = A.w - prev.w;
    gyb = e0 * e0 + e1 * e1 + e2 * e2 + e3 * e3;
  }
#undef SUMS_GX

  for (int i = t; i < NCHUNK * NSTAT; i += 320) acc[i] = 0.f;
  __syncthreads();
  if (active) {
    const int chunk = tc / 12;
    atomicAdd(&acc[chunk * NSTAT + 0], s1);
    atomicAdd(&acc[chunk * NSTAT + 1], s2);
    atomicAdd(&acc[chunk * NSTAT + 2], gxi);
    atomicAdd(&acc[chunk * NSTAT + 3], gxb);
    atomicAdd(&acc[chunk * NSTAT + 4], gyi);
    atomicAdd(&acc[chunk * NSTAT + 5], gyb);
  }
  __syncthreads();
  float* dst = pf + (size_t)(bc * NHB + hb) * (NCHUNK * NSTAT);
  for (int i = t; i < NCHUNK * NSTAT; i += 320) dst[i] = acc[i];
}

// ---------------------------------------------------------------------------
// Phase 2+3 merged: one block per bc (32 blocks). Stage the bc's 44x22x6 slab
// in LDS; thread p<441 combines its 4 half-bands x 2 chunks into
// (mu, var, gmag); block-reduce to per-bc means -> featsG. The last-arriving
// block (device-scope ticket; only 32 fences, cheap) then runs the
// register-resident Gauss-Jordan + Mahalanobis finalize. Validated round 2.
// ---------------------------------------------------------------------------
__global__ __launch_bounds__(512) void patch_finalize_kernel(
    const float* __restrict__ pf, float* __restrict__ featsG,
    int* __restrict__ cnt, const float* __restrict__ mu0_full,
    const float* __restrict__ cov_full, float* __restrict__ out) {
  __shared__ float S[SLAB];                   // 23.2 KB
  __shared__ float wsum[8][3];
  __shared__ double inv_s[12][12];
  __shared__ float fin_s[96 + BATCH];
  __shared__ int ticket_s;

  const int bc = blockIdx.x;
  const int t = threadIdx.x;
  const float* src = pf + (size_t)bc * SLAB;
  for (int i = t; i < SLAB; i += 512) S[i] = src[i];
  __syncthreads();

  float fmu = 0.f, fvar = 0.f, fg = 0.f;
  if (t < NP) {
    const int ph = t / NW, pw = t - ph * NW;
    const int h0 = 2 * ph;
#define AT(h, c, s) S[((h) * NCHUNK + (c)) * NSTAT + (s)]
    float S1 = 0.f, S2 = 0.f, Gx = 0.f, Gy = 0.f;
#pragma unroll
    for (int hh = 0; hh < 4; ++hh) {
      const int h = h0 + hh;
      S1 += AT(h, pw, 0) + AT(h, pw + 1, 0);
      S2 += AT(h, pw, 1) + AT(h, pw + 1, 1);
      Gx += AT(h, pw, 2) + AT(h, pw, 3) + AT(h, pw + 1, 2);
      Gy += AT(h, pw, 4) + AT(h, pw + 1, 4);
    }
#pragma unroll
    for (int hh = 0; hh < 3; ++hh) {
      const int h = h0 + hh;
      Gy += AT(h, pw, 5) + AT(h, pw + 1, 5);
    }
#undef AT
    fmu = S1 / NPIX;
    fvar = (S2 - S1 * S1 / NPIX) / (NPIX - 1.f);
    fg = sqrtf((Gx + Gy) / NGRAD);
  }
#pragma unroll
  for (int off = 32; off > 0; off >>= 1) {
    fmu += __shfl_xor(fmu, off);
    fvar += __shfl_xor(fvar, off);
    fg += __shfl_xor(fg, off);
  }
  const int wave = t >> 6;
  if ((t & 63) == 0) { wsum[wave][0] = fmu; wsum[wave][1] = fvar; wsum[wave][2] = fg; }
  __syncthreads();
  if (t == 0) {
    float m = 0.f, v = 0.f, g = 0.f;
#pragma unroll
    for (int w = 0; w < 8; ++w) { m += wsum[w][0]; v += wsum[w][1]; g += wsum[w][2]; }
    const int b = bc / CHAN, c = bc - b * CHAN;
    featsG[b * 12 + 0 + c] = m / (float)NP;
    featsG[b * 12 + 4 + c] = v / (float)NP;
    featsG[b * 12 + 8 + c] = g / (float)NP;
    __threadfence();                      // release featsG (L2 writeback)
    ticket_s = atomicAdd(cnt, 1);         // device-scope ticket
  }
  __syncthreads();
  if (ticket_s != NBC - 1) return;

  // ---- last block: finalize ----
  __threadfence();                        // acquire: invalidate stale lines
  if (t < 96)
    fin_s[t] = __hip_atomic_load(&featsG[t], __ATOMIC_RELAXED,
                                 __HIP_MEMORY_SCOPE_AGENT);
  __syncthreads();

  if (t < 64) {   // wave 0: register-resident Gauss-Jordan, lane c owns col c
    double M[12];
#pragma unroll
    for (int r = 0; r < 12; ++r) {
      double v = 0.0;
      if (t < 12) v = (double)cov_full[r * 36 + t];
      else if (t < 24) v = (t - 12 == r) ? 1.0 : 0.0;
      M[r] = v;
    }
#pragma unroll
    for (int k = 0; k < 12; ++k) {
      const double piv = __shfl(M[k], k);
      const double ip = 1.0 / piv;
      M[k] *= ip;
#pragma unroll
      for (int r = 0; r < 12; ++r) {
        if (r == k) continue;
        const double f = __shfl(M[r], k);   // old M[r][k], read before update
        M[r] -= f * M[k];
      }
    }
    if (t >= 12 && t < 24) {
      const int j = t - 12;
#pragma unroll
      for (int r = 0; r < 12; ++r) inv_s[r][j] = M[r];
    }
  }
  __syncthreads();

  if (t < BATCH) {
    double acc = 0.0;
    double d[12];
#pragma unroll
    for (int i = 0; i < 12; ++i)
      d[i] = (double)fin_s[t * 12 + i] - (double)mu0_full[i];
#pragma unroll
    for (int i = 0; i < 12; ++i) {
      double row = 0.0;
#pragma unroll
      for (int j = 0; j < 12; ++j) row += inv_s[i][j] * d[j];
      acc += d[i] * row;
    }
    fin_s[96 + t] = (float)sqrt(acc);
  }
  __syncthreads();
  if (t == 0) {
    float m = 0.f;
#pragma unroll
    for (int b = 0; b < BATCH; ++b) m += fin_s[96 + b];
    out[0] = m / (float)BATCH;
  }
}

extern "C" void kernel_launch(void* const* d_in, const int* in_sizes, int n_in,
                              void* d_out, int out_size, void* d_ws, size_t ws_size,
                              hipStream_t stream) {
  const float* x   = (const float*)d_in[0];
  const float* mu0 = (const float*)d_in[1];
  const float* cov = (const float*)d_in[2];
  float* out = (float*)d_out;
  float* pf     = (float*)d_ws;                         // 32*5808 floats = 743 KB
  float* featsG = pf + (size_t)NBC * SLAB;              // 96 floats
  int* cnt      = (int*)(featsG + 96);                  // 1 ticket counter

  band_stats_kernel<<<NBC * NHB, 320, 0, stream>>>(x, pf, cnt);
  patch_finalize_kernel<<<NBC, 512, 0, stream>>>(pf, featsG, cnt, mu0, cov, out);
}